// Round 15
// baseline (144.361 us; speedup 1.0000x reference)
//
#include <hip/hip_runtime.h>
#include <hip/hip_bf16.h>

#define NB   4
#define NL   9
#define NQ   300
#define LQ   2700
#define NS   100
#define NC   256
#define NCLS 81
#define NPX  25600
#define EPSV 1e-6f

#define MASKS_BASE 32400
#define EMB_BASE   10272400   // 32400 + 4*100*160*160

#define A_STRIDE 264          // bf16 elems; 528B rows
#define BP_STRIDE 260         // f32 per pair: 2 rows x 128 px + 4 pad
#define B_BUF_F  (16 * BP_STRIDE)   // 4160 f32 per buffer

typedef short bf16x8 __attribute__((ext_vector_type(8)));
typedef short bf16x4 __attribute__((ext_vector_type(4)));
typedef float f32x4  __attribute__((ext_vector_type(4)));

__device__ inline unsigned short f2bf(float f) {
    __hip_bfloat16 h = __float2bfloat16(f);
    return *reinterpret_cast<unsigned short*>(&h);
}

// K1 (MFMA): sim = seed x qsig^T per b.  Round-14 version (passed).
__global__ __launch_bounds__(256) void k_sim_mfma(const float* __restrict__ qsig,
                                                  const float* __restrict__ seed,
                                                  const int* __restrict__ mask,
                                                  float* __restrict__ w,
                                                  float* __restrict__ dsum) {
    __shared__ unsigned short As[64 * A_STRIDE];   // 33792 B

    const int b      = blockIdx.y;
    const int q0     = blockIdx.x * 128;
    const int zhalf  = blockIdx.z;          // 0: s 0..63, 1: s 64..99
    const int s_base = zhalf * 64;
    const int st_max = 4 - zhalf;
    const int tid    = threadIdx.x;
    const float* seedb = seed + (size_t)b * NS * NC;

    const int lane = tid & 63;
    const int wv   = tid >> 6;
    const int lg   = lane >> 4;
    const int ll   = lane & 15;

    const int qA = q0 + wv * 32 + ll;
    const int qB = qA + 16;
    const bool okA = (qA < LQ);
    const bool okB = (qB < LQ);
    const int qAc = okA ? qA : LQ - 1;
    const int qBc = okB ? qB : LQ - 1;
    const int lA = qAc / NQ, rA = qAc - lA * NQ;
    const int lB = qBc / NQ, rB = qBc - lB * NQ;
    const float* rowA = qsig + ((size_t)((lA * NB + b) * NQ + rA)) * NC;
    const float* rowB = qsig + ((size_t)((lB * NB + b) * NQ + rB)) * NC;

    float4 pA0 = *(const float4*)(rowA + lg * 8);
    float4 pA1 = *(const float4*)(rowA + lg * 8 + 4);
    float4 pB0 = *(const float4*)(rowB + lg * 8);
    float4 pB1 = *(const float4*)(rowB + lg * 8 + 4);

    const int rows_data = zhalf ? 36 : 64;
    for (int u = tid; u < rows_data * 64; u += 256) {
        const int s  = u >> 6;
        const int k4 = (u & 63) << 2;
        const float4 v = *(const float4*)(seedb + (size_t)(s_base + s) * NC + k4);
        bf16x4 pv;
        pv[0] = (short)f2bf(v.x); pv[1] = (short)f2bf(v.y);
        pv[2] = (short)f2bf(v.z); pv[3] = (short)f2bf(v.w);
        *(bf16x4*)&As[s * A_STRIDE + k4] = pv;
    }
    if (zhalf) {
        bf16x4 z; z[0] = 0; z[1] = 0; z[2] = 0; z[3] = 0;
        for (int u = tid; u < (12 * A_STRIDE) / 4; u += 256)
            *(bf16x4*)&As[36 * A_STRIDE + u * 4] = z;
    }
    __syncthreads();

    f32x4 acc[4][2];
    #pragma unroll
    for (int st = 0; st < 4; ++st) {
        acc[st][0] = (f32x4)(0.f);
        acc[st][1] = (f32x4)(0.f);
    }

    #pragma unroll
    for (int kk = 0; kk < 8; ++kk) {
        float4 nA0, nA1, nB0, nB1;
        if (kk < 7) {
            nA0 = *(const float4*)(rowA + (kk + 1) * 32 + lg * 8);
            nA1 = *(const float4*)(rowA + (kk + 1) * 32 + lg * 8 + 4);
            nB0 = *(const float4*)(rowB + (kk + 1) * 32 + lg * 8);
            nB1 = *(const float4*)(rowB + (kk + 1) * 32 + lg * 8 + 4);
        }

        bf16x8 bf0, bf1;
        bf0[0] = (short)f2bf(pA0.x); bf0[1] = (short)f2bf(pA0.y);
        bf0[2] = (short)f2bf(pA0.z); bf0[3] = (short)f2bf(pA0.w);
        bf0[4] = (short)f2bf(pA1.x); bf0[5] = (short)f2bf(pA1.y);
        bf0[6] = (short)f2bf(pA1.z); bf0[7] = (short)f2bf(pA1.w);
        bf1[0] = (short)f2bf(pB0.x); bf1[1] = (short)f2bf(pB0.y);
        bf1[2] = (short)f2bf(pB0.z); bf1[3] = (short)f2bf(pB0.w);
        bf1[4] = (short)f2bf(pB1.x); bf1[5] = (short)f2bf(pB1.y);
        bf1[6] = (short)f2bf(pB1.z); bf1[7] = (short)f2bf(pB1.w);
        if (!okA) {
            #pragma unroll
            for (int j = 0; j < 8; ++j) bf0[j] = 0;
        }
        if (!okB) {
            #pragma unroll
            for (int j = 0; j < 8; ++j) bf1[j] = 0;
        }

        #pragma unroll
        for (int st = 0; st < 4; ++st) {
            if (st < st_max) {
                const bf16x8 af = *(const bf16x8*)&As[(st * 16 + ll) * A_STRIDE + kk * 32 + lg * 8];
                acc[st][0] = __builtin_amdgcn_mfma_f32_16x16x32_bf16(af, bf0, acc[st][0], 0, 0, 0);
                acc[st][1] = __builtin_amdgcn_mfma_f32_16x16x32_bf16(af, bf1, acc[st][1], 0, 0, 0);
            }
        }

        pA0 = nA0; pA1 = nA1; pB0 = nB0; pB1 = nB1;
    }

    #pragma unroll
    for (int st = 0; st < 4; ++st) {
        if (st < st_max) {
            #pragma unroll
            for (int r = 0; r < 4; ++r) {
                const int s = s_base + st * 16 + lg * 4 + r;
                if (s < NS) {
                    const float vm = (mask[b * NS + s] != 0) ? 1.0f : 0.0f;
                    float v0 = acc[st][0][r]; v0 = (v0 > 0.f ? v0 : 0.f) * vm;
                    float v1 = acc[st][1][r]; v1 = (v1 > 0.f ? v1 : 0.f) * vm;
                    float* wrow = w + ((size_t)(b * NS + s)) * LQ;
                    if (okA) wrow[qA] = v0;
                    if (okB) wrow[qB] = v1;
                    float t = v0 + v1;
                    t += __shfl_xor(t, 1);
                    t += __shfl_xor(t, 2);
                    t += __shfl_xor(t, 4);
                    t += __shfl_xor(t, 8);
                    if (ll == 0) atomicAdd(&dsum[b * NS + s], t);
                }
            }
        }
    }
}

// K3: fused emb+cls reduction over q, split-K atomics
__global__ __launch_bounds__(256) void k_embcls(const float* __restrict__ w,
                                                const float* __restrict__ qemb,
                                                const float* __restrict__ qcls,
                                                float* __restrict__ out_emb,
                                                float* __restrict__ out_cls) {
    __shared__ float W[NS * 128];
    const int t  = blockIdx.x;
    const int b  = blockIdx.y;
    const int qc = blockIdx.z;
    const int q0 = qc * 128;
    const int q1 = min(128, LQ - q0);

    for (int i = threadIdx.x; i < NS * 32; i += 256) {
        const int s  = i >> 5;
        const int q4 = (i & 31) << 2;
        if (q4 < q1)
            *(float4*)&W[s * 128 + q4] =
                *(const float4*)(w + ((size_t)(b * NS + s)) * LQ + q0 + q4);
    }
    __syncthreads();

    const int cl = threadIdx.x & 63;
    const int y  = threadIdx.x >> 6;
    const float* src; int ncols, c0; float* dst;
    if (t < 4) { src = qemb; ncols = NC;   c0 = t * 64;       dst = out_emb; }
    else       { src = qcls; ncols = NCLS; c0 = (t - 4) * 64; dst = out_cls; }
    const int  c   = c0 + cl;
    const bool act = (c < ncols);

    float acc[25];
    #pragma unroll
    for (int j = 0; j < 25; ++j) acc[j] = 0.f;

    for (int qq = 0; qq < q1; qq += 4) {
        float bv[4];
        #pragma unroll
        for (int k = 0; k < 4; ++k) {
            const int q = q0 + qq + k;
            const int l = q / NQ;
            const int r = q - l * NQ;
            bv[k] = act ? src[((size_t)((l * NB + b) * NQ + r)) * ncols + c] : 0.f;
        }
        const float* wp = &W[(y * 25) * 128 + qq];
        #pragma unroll
        for (int j = 0; j < 25; ++j) {
            const float4 wv = *(const float4*)(wp + j * 128);
            acc[j] = fmaf(wv.x, bv[0], fmaf(wv.y, bv[1],
                     fmaf(wv.z, bv[2], fmaf(wv.w, bv[3], acc[j]))));
        }
    }
    if (act) {
        #pragma unroll
        for (int j = 0; j < 25; ++j) {
            const int s = y * 25 + j;
            atomicAdd(dst + ((size_t)(b * NS + s)) * ncols + c, acc[j]);
        }
    }
}

// K4: scale accumulated sums by 1/max(dsum,eps)
__global__ __launch_bounds__(256) void k_fin(float* __restrict__ out,
                                             const float* __restrict__ dsum) {
    const int i = blockIdx.x * 256 + threadIdx.x;
    if (i < NB * NS * NCLS) {
        const int b = i / (NS * NCLS);
        const int s = (i / NCLS) % NS;
        const float d = dsum[b * NS + s];
        out[i] *= 1.0f / (d > EPSV ? d : EPSV);
    } else if (i < NB * NS * NCLS + NB * NS * NC) {
        const int j = i - NB * NS * NCLS;
        const int b = j / (NS * NC);
        const int s = (j >> 8) % NS;
        const float d = dsum[b * NS + s];
        out[EMB_BASE + j] *= 1.0f / (d > EPSV ? d : EPSV);
    }
}

// K5 (MFMA): proto_masks[b][s][px] = sum_c emb[b][s][c] * mf[b][c][px]
// B staged f32 via global_load_lds into paired-row LDS (260-f32 pairs),
// double-buffered with COUNTED vmcnt(4) + raw barriers: staging loads for
// step kk+1 stay in flight across the whole step (never drained to 0).
__global__ __launch_bounds__(256) void k_masks_mfma(const float* __restrict__ emb,
                                                    const float* __restrict__ mf,
                                                    float* __restrict__ outm) {
    __shared__ unsigned short As[64 * A_STRIDE];   // 33792 B
    __shared__ float BsF[2 * B_BUF_F];             // 33280 B (total 67072)

    const int b      = blockIdx.y;
    const int px0    = blockIdx.x * 128;
    const int zhalf  = blockIdx.z;          // 0: s 0..63, 1: s 64..99
    const int s_base = zhalf * 64;
    const int st_max = 4 - zhalf;
    const int tid    = threadIdx.x;
    const float* mfb  = mf  + (size_t)b * NC * NPX;
    const float* embb = emb + (size_t)b * NS * NC;

    const int lane = tid & 63;
    const int wv   = tid >> 6;
    const int lg   = lane >> 4;
    const int ll   = lane & 15;

    // per-lane source offsets for gload_lds (pair kp -> rows 2kp, 2kp+1)
    const int src_row = lane >> 5;           // 0/1 within pair
    const int src_px4 = (lane & 31) << 2;

    // ---- prologue: issue B(0) into buf 0 (zero-VGPR async) ----
    #pragma unroll
    for (int i = 0; i < 4; ++i) {
        const int kp = wv * 4 + i;
        const float* src = mfb + (size_t)(2 * kp + src_row) * NPX + px0 + src_px4;
        __builtin_amdgcn_global_load_lds(
            (const __attribute__((address_space(1))) void*)src,
            (__attribute__((address_space(3))) void*)&BsF[kp * BP_STRIDE],
            16, 0, 0);
    }

    // ---- stage A (f32 -> bf16), pad rows zero ----
    const int rows_data = zhalf ? 36 : 64;
    for (int u = tid; u < rows_data * 64; u += 256) {
        const int r  = u >> 6;
        const int k4 = (u & 63) << 2;
        const float4 v = *(const float4*)(embb + (size_t)(s_base + r) * NC + k4);
        bf16x4 pv;
        pv[0] = (short)f2bf(v.x); pv[1] = (short)f2bf(v.y);
        pv[2] = (short)f2bf(v.z); pv[3] = (short)f2bf(v.w);
        *(bf16x4*)&As[r * A_STRIDE + k4] = pv;
    }
    if (zhalf) {
        bf16x4 z; z[0] = 0; z[1] = 0; z[2] = 0; z[3] = 0;
        for (int u = tid; u < (12 * A_STRIDE) / 4; u += 256)
            *(bf16x4*)&As[36 * A_STRIDE + u * 4] = z;
    }
    __syncthreads();   // drains prologue loads; A + B(0) ready

    f32x4 acc[4][2];
    #pragma unroll
    for (int st = 0; st < 4; ++st) {
        acc[st][0] = (f32x4)(0.f);
        acc[st][1] = (f32x4)(0.f);
    }

    const int pxF = wv * 32 + ll;      // + ct*16

    #pragma unroll
    for (int kk = 0; kk < 8; ++kk) {
        const int cur = (kk & 1) * B_BUF_F;

        // issue next step's staging; wait only for CURRENT buffer's loads
        if (kk < 7) {
            const int nxt = ((kk + 1) & 1) * B_BUF_F;
            #pragma unroll
            for (int i = 0; i < 4; ++i) {
                const int kp = wv * 4 + i;
                const float* src = mfb + (size_t)((kk + 1) * 32 + 2 * kp + src_row) * NPX + px0 + src_px4;
                __builtin_amdgcn_global_load_lds(
                    (const __attribute__((address_space(1))) void*)src,
                    (__attribute__((address_space(3))) void*)&BsF[nxt + kp * BP_STRIDE],
                    16, 0, 0);
            }
            asm volatile("s_waitcnt vmcnt(4)" ::: "memory");
        } else {
            asm volatile("s_waitcnt vmcnt(0)" ::: "memory");
        }
        __builtin_amdgcn_s_barrier();          // all waves' cur-loads landed
        __builtin_amdgcn_sched_barrier(0);

        // B fragments: paired-row reads (2-way banks = free) + cvt
        bf16x8 bf0, bf1;
        #pragma unroll
        for (int j = 0; j < 8; ++j) {
            const int off = cur + (4 * lg + (j >> 1)) * BP_STRIDE + (j & 1) * 128 + pxF;
            bf0[j] = (short)f2bf(BsF[off]);
            bf1[j] = (short)f2bf(BsF[off + 16]);
        }

        #pragma unroll
        for (int st = 0; st < 4; ++st) {
            if (st < st_max) {
                const bf16x8 af = *(const bf16x8*)&As[(st * 16 + ll) * A_STRIDE + kk * 32 + lg * 8];
                acc[st][0] = __builtin_amdgcn_mfma_f32_16x16x32_bf16(af, bf0, acc[st][0], 0, 0, 0);
                acc[st][1] = __builtin_amdgcn_mfma_f32_16x16x32_bf16(af, bf1, acc[st][1], 0, 0, 0);
            }
        }

        __builtin_amdgcn_sched_barrier(0);
        __builtin_amdgcn_s_barrier();          // reads done before buf reuse
    }

    #pragma unroll
    for (int st = 0; st < 4; ++st) {
        if (st < st_max) {
            #pragma unroll
            for (int ct = 0; ct < 2; ++ct) {
                #pragma unroll
                for (int r = 0; r < 4; ++r) {
                    const int s = s_base + st * 16 + lg * 4 + r;
                    if (s < NS)
                        outm[((size_t)(b * NS + s)) * NPX + px0 + wv * 32 + ct * 16 + ll] = acc[st][ct][r];
                }
            }
        }
    }
}

extern "C" void kernel_launch(void* const* d_in, const int* in_sizes, int n_in,
                              void* d_out, int out_size, void* d_ws, size_t ws_size,
                              hipStream_t stream) {
    const float* qcls = (const float*)d_in[0];
    const float* qemb = (const float*)d_in[1];
    const float* qsig = (const float*)d_in[2];
    const float* seed = (const float*)d_in[3];
    const float* mf   = (const float*)d_in[4];
    const int*   mask = (const int*)d_in[5];

    float* out       = (float*)d_out;
    float* out_cls   = out;
    float* out_masks = out + MASKS_BASE;
    float* out_emb   = out + EMB_BASE;

    float* w    = (float*)d_ws;                    // [4][100][2700]
    float* dsum = w + (size_t)NB * NS * LQ;        // [400]

    hipMemsetAsync(out_cls, 0, (size_t)NB * NS * NCLS * sizeof(float), stream);
    hipMemsetAsync(out_emb, 0, (size_t)NB * NS * NC * sizeof(float), stream);
    hipMemsetAsync(dsum,    0, (size_t)NB * NS * sizeof(float), stream);

    k_sim_mfma<<<dim3(22, NB, 2), 256, 0, stream>>>(qsig, seed, mask, w, dsum);
    k_embcls  <<<dim3(6, NB, 22), 256, 0, stream>>>(w, qemb, qcls, out_emb, out_cls);
    k_fin     <<<527,             256, 0, stream>>>(out, dsum);
    k_masks_mfma<<<dim3(200, NB, 2), 256, 0, stream>>>(out_emb, mf, out_masks);
}

// Round 16
// 125.828 us; speedup vs baseline: 1.1473x; 1.1473x over previous
//
#include <hip/hip_runtime.h>
#include <hip/hip_bf16.h>

#define NB   4
#define NL   9
#define NQ   300
#define LQ   2700
#define NS   100
#define NC   256
#define NCLS 81
#define NPX  25600
#define EPSV 1e-6f

#define MASKS_BASE 32400
#define EMB_BASE   10272400   // 32400 + 4*100*160*160

#define A_STRIDE 264          // bf16 elems; 528B rows: 16B-aligned, 4-bank rotation
#define B_STRIDE 260          // bf16 elems per k-row of B_lds (256 px + 4 pad)
#define B_BUF    (32 * B_STRIDE)

typedef short bf16x8 __attribute__((ext_vector_type(8)));
typedef short bf16x4 __attribute__((ext_vector_type(4)));
typedef float f32x4  __attribute__((ext_vector_type(4)));

__device__ inline unsigned short f2bf(float f) {
    __hip_bfloat16 h = __float2bfloat16(f);
    return *reinterpret_cast<unsigned short*>(&h);
}

// K1 (MFMA): sim = seed x qsig^T per b.  Round-14 version (passed, best).
__global__ __launch_bounds__(256) void k_sim_mfma(const float* __restrict__ qsig,
                                                  const float* __restrict__ seed,
                                                  const int* __restrict__ mask,
                                                  float* __restrict__ w,
                                                  float* __restrict__ dsum) {
    __shared__ unsigned short As[64 * A_STRIDE];   // 33792 B

    const int b      = blockIdx.y;
    const int q0     = blockIdx.x * 128;
    const int zhalf  = blockIdx.z;          // 0: s 0..63, 1: s 64..99
    const int s_base = zhalf * 64;
    const int st_max = 4 - zhalf;
    const int tid    = threadIdx.x;
    const float* seedb = seed + (size_t)b * NS * NC;

    const int lane = tid & 63;
    const int wv   = tid >> 6;
    const int lg   = lane >> 4;
    const int ll   = lane & 15;

    const int qA = q0 + wv * 32 + ll;
    const int qB = qA + 16;
    const bool okA = (qA < LQ);
    const bool okB = (qB < LQ);
    const int qAc = okA ? qA : LQ - 1;
    const int qBc = okB ? qB : LQ - 1;
    const int lA = qAc / NQ, rA = qAc - lA * NQ;
    const int lB = qBc / NQ, rB = qBc - lB * NQ;
    const float* rowA = qsig + ((size_t)((lA * NB + b) * NQ + rA)) * NC;
    const float* rowB = qsig + ((size_t)((lB * NB + b) * NQ + rB)) * NC;

    float4 pA0 = *(const float4*)(rowA + lg * 8);
    float4 pA1 = *(const float4*)(rowA + lg * 8 + 4);
    float4 pB0 = *(const float4*)(rowB + lg * 8);
    float4 pB1 = *(const float4*)(rowB + lg * 8 + 4);

    const int rows_data = zhalf ? 36 : 64;
    for (int u = tid; u < rows_data * 64; u += 256) {
        const int s  = u >> 6;
        const int k4 = (u & 63) << 2;
        const float4 v = *(const float4*)(seedb + (size_t)(s_base + s) * NC + k4);
        bf16x4 pv;
        pv[0] = (short)f2bf(v.x); pv[1] = (short)f2bf(v.y);
        pv[2] = (short)f2bf(v.z); pv[3] = (short)f2bf(v.w);
        *(bf16x4*)&As[s * A_STRIDE + k4] = pv;
    }
    if (zhalf) {
        bf16x4 z; z[0] = 0; z[1] = 0; z[2] = 0; z[3] = 0;
        for (int u = tid; u < (12 * A_STRIDE) / 4; u += 256)
            *(bf16x4*)&As[36 * A_STRIDE + u * 4] = z;
    }
    __syncthreads();

    f32x4 acc[4][2];
    #pragma unroll
    for (int st = 0; st < 4; ++st) {
        acc[st][0] = (f32x4)(0.f);
        acc[st][1] = (f32x4)(0.f);
    }

    #pragma unroll
    for (int kk = 0; kk < 8; ++kk) {
        float4 nA0, nA1, nB0, nB1;
        if (kk < 7) {
            nA0 = *(const float4*)(rowA + (kk + 1) * 32 + lg * 8);
            nA1 = *(const float4*)(rowA + (kk + 1) * 32 + lg * 8 + 4);
            nB0 = *(const float4*)(rowB + (kk + 1) * 32 + lg * 8);
            nB1 = *(const float4*)(rowB + (kk + 1) * 32 + lg * 8 + 4);
        }

        bf16x8 bf0, bf1;
        bf0[0] = (short)f2bf(pA0.x); bf0[1] = (short)f2bf(pA0.y);
        bf0[2] = (short)f2bf(pA0.z); bf0[3] = (short)f2bf(pA0.w);
        bf0[4] = (short)f2bf(pA1.x); bf0[5] = (short)f2bf(pA1.y);
        bf0[6] = (short)f2bf(pA1.z); bf0[7] = (short)f2bf(pA1.w);
        bf1[0] = (short)f2bf(pB0.x); bf1[1] = (short)f2bf(pB0.y);
        bf1[2] = (short)f2bf(pB0.z); bf1[3] = (short)f2bf(pB0.w);
        bf1[4] = (short)f2bf(pB1.x); bf1[5] = (short)f2bf(pB1.y);
        bf1[6] = (short)f2bf(pB1.z); bf1[7] = (short)f2bf(pB1.w);
        if (!okA) {
            #pragma unroll
            for (int j = 0; j < 8; ++j) bf0[j] = 0;
        }
        if (!okB) {
            #pragma unroll
            for (int j = 0; j < 8; ++j) bf1[j] = 0;
        }

        #pragma unroll
        for (int st = 0; st < 4; ++st) {
            if (st < st_max) {
                const bf16x8 af = *(const bf16x8*)&As[(st * 16 + ll) * A_STRIDE + kk * 32 + lg * 8];
                acc[st][0] = __builtin_amdgcn_mfma_f32_16x16x32_bf16(af, bf0, acc[st][0], 0, 0, 0);
                acc[st][1] = __builtin_amdgcn_mfma_f32_16x16x32_bf16(af, bf1, acc[st][1], 0, 0, 0);
            }
        }

        pA0 = nA0; pA1 = nA1; pB0 = nB0; pB1 = nB1;
    }

    #pragma unroll
    for (int st = 0; st < 4; ++st) {
        if (st < st_max) {
            #pragma unroll
            for (int r = 0; r < 4; ++r) {
                const int s = s_base + st * 16 + lg * 4 + r;
                if (s < NS) {
                    const float vm = (mask[b * NS + s] != 0) ? 1.0f : 0.0f;
                    float v0 = acc[st][0][r]; v0 = (v0 > 0.f ? v0 : 0.f) * vm;
                    float v1 = acc[st][1][r]; v1 = (v1 > 0.f ? v1 : 0.f) * vm;
                    float* wrow = w + ((size_t)(b * NS + s)) * LQ;
                    if (okA) wrow[qA] = v0;
                    if (okB) wrow[qB] = v1;
                    float t = v0 + v1;
                    t += __shfl_xor(t, 1);
                    t += __shfl_xor(t, 2);
                    t += __shfl_xor(t, 4);
                    t += __shfl_xor(t, 8);
                    if (ll == 0) atomicAdd(&dsum[b * NS + s], t);
                }
            }
        }
    }
}

// K3: fused emb+cls reduction over q, split-K atomics
__global__ __launch_bounds__(256) void k_embcls(const float* __restrict__ w,
                                                const float* __restrict__ qemb,
                                                const float* __restrict__ qcls,
                                                float* __restrict__ out_emb,
                                                float* __restrict__ out_cls) {
    __shared__ float W[NS * 128];
    const int t  = blockIdx.x;
    const int b  = blockIdx.y;
    const int qc = blockIdx.z;
    const int q0 = qc * 128;
    const int q1 = min(128, LQ - q0);

    for (int i = threadIdx.x; i < NS * 32; i += 256) {
        const int s  = i >> 5;
        const int q4 = (i & 31) << 2;
        if (q4 < q1)
            *(float4*)&W[s * 128 + q4] =
                *(const float4*)(w + ((size_t)(b * NS + s)) * LQ + q0 + q4);
    }
    __syncthreads();

    const int cl = threadIdx.x & 63;
    const int y  = threadIdx.x >> 6;
    const float* src; int ncols, c0; float* dst;
    if (t < 4) { src = qemb; ncols = NC;   c0 = t * 64;       dst = out_emb; }
    else       { src = qcls; ncols = NCLS; c0 = (t - 4) * 64; dst = out_cls; }
    const int  c   = c0 + cl;
    const bool act = (c < ncols);

    float acc[25];
    #pragma unroll
    for (int j = 0; j < 25; ++j) acc[j] = 0.f;

    for (int qq = 0; qq < q1; qq += 4) {
        float bv[4];
        #pragma unroll
        for (int k = 0; k < 4; ++k) {
            const int q = q0 + qq + k;
            const int l = q / NQ;
            const int r = q - l * NQ;
            bv[k] = act ? src[((size_t)((l * NB + b) * NQ + r)) * ncols + c] : 0.f;
        }
        const float* wp = &W[(y * 25) * 128 + qq];
        #pragma unroll
        for (int j = 0; j < 25; ++j) {
            const float4 wv = *(const float4*)(wp + j * 128);
            acc[j] = fmaf(wv.x, bv[0], fmaf(wv.y, bv[1],
                     fmaf(wv.z, bv[2], fmaf(wv.w, bv[3], acc[j]))));
        }
    }
    if (act) {
        #pragma unroll
        for (int j = 0; j < 25; ++j) {
            const int s = y * 25 + j;
            atomicAdd(dst + ((size_t)(b * NS + s)) * ncols + c, acc[j]);
        }
    }
}

// K4: scale accumulated sums by 1/max(dsum,eps)
__global__ __launch_bounds__(256) void k_fin(float* __restrict__ out,
                                             const float* __restrict__ dsum) {
    const int i = blockIdx.x * 256 + threadIdx.x;
    if (i < NB * NS * NCLS) {
        const int b = i / (NS * NCLS);
        const int s = (i / NCLS) % NS;
        const float d = dsum[b * NS + s];
        out[i] *= 1.0f / (d > EPSV ? d : EPSV);
    } else if (i < NB * NS * NCLS + NB * NS * NC) {
        const int j = i - NB * NS * NCLS;
        const int b = j / (NS * NC);
        const int s = (j >> 8) % NS;
        const float d = dsum[b * NS + s];
        out[EMB_BASE + j] *= 1.0f / (d > EPSV ? d : EPSV);
    }
}

// K5 (MFMA): proto_masks[b][s][px] = sum_c emb[b][s][c] * mf[b][c][px]
// Round-14 body; grid flattened to 800 with bijective XCD-chunk swizzle
// (800%8==0) and zhalf as the FASTEST bit of the swizzled id -> the two
// zhalf twins sharing one mf slice are co-resident on the same XCD's L2.
__global__ __launch_bounds__(256, 2) void k_masks_mfma(const float* __restrict__ emb,
                                                       const float* __restrict__ mf,
                                                       float* __restrict__ outm) {
    __shared__ unsigned short As[64 * A_STRIDE];   // 33792 B
    __shared__ unsigned short Bs[2 * B_BUF];       // 33280 B  (total 67072)

    // XCD swizzle: orig -> chunked work id (bijective, nwg=800)
    const int orig  = blockIdx.x;
    const int wgid  = (orig & 7) * 100 + (orig >> 3);
    const int zhalf = wgid & 1;             // twins have consecutive wgid
    const int rest  = wgid >> 1;            // 0..399
    const int pxt   = rest % 100;
    const int b     = rest / 100;           // 0..3

    const int px0    = pxt * 256;
    const int s_base = zhalf * 64;
    const int st_max = 4 - zhalf;
    const int tid    = threadIdx.x;
    const float* mfb  = mf  + (size_t)b * NC * NPX;
    const float* embb = emb + (size_t)b * NS * NC;

    const int lane = tid & 63;
    const int wv   = tid >> 6;
    const int lg   = lane >> 4;
    const int ll   = lane & 15;

    const int stg_k   = tid >> 6;          // 0..3
    const int stg_px4 = (tid & 63) << 2;   // 0..252

    float4 bv[8];
    #pragma unroll
    for (int i = 0; i < 8; ++i)
        bv[i] = *(const float4*)(mfb + (size_t)(stg_k + i * 4) * NPX + px0 + stg_px4);

    const int rows_data = zhalf ? 36 : 64;
    for (int u = tid; u < rows_data * 64; u += 256) {
        const int r  = u >> 6;
        const int k4 = (u & 63) << 2;
        const float4 v = *(const float4*)(embb + (size_t)(s_base + r) * NC + k4);
        bf16x4 pv;
        pv[0] = (short)f2bf(v.x); pv[1] = (short)f2bf(v.y);
        pv[2] = (short)f2bf(v.z); pv[3] = (short)f2bf(v.w);
        *(bf16x4*)&As[r * A_STRIDE + k4] = pv;
    }
    if (zhalf) {
        bf16x4 z; z[0] = 0; z[1] = 0; z[2] = 0; z[3] = 0;
        for (int u = tid; u < (12 * A_STRIDE) / 4; u += 256)
            *(bf16x4*)&As[36 * A_STRIDE + u * 4] = z;
    }

    #pragma unroll
    for (int i = 0; i < 8; ++i) {
        bf16x4 pv;
        pv[0] = (short)f2bf(bv[i].x); pv[1] = (short)f2bf(bv[i].y);
        pv[2] = (short)f2bf(bv[i].z); pv[3] = (short)f2bf(bv[i].w);
        *(bf16x4*)&Bs[(stg_k + i * 4) * B_STRIDE + stg_px4] = pv;
    }
    __syncthreads();

    f32x4 acc[4][4];
    #pragma unroll
    for (int st = 0; st < 4; ++st)
        #pragma unroll
        for (int ct = 0; ct < 4; ++ct) acc[st][ct] = (f32x4)(0.f);

    const int pxF = wv * 64 + ll;      // + ct*16

    #pragma unroll
    for (int kk = 0; kk < 8; ++kk) {
        const int cur = (kk & 1) * B_BUF;

        float4 nv[8];
        if (kk < 7) {
            #pragma unroll
            for (int i = 0; i < 8; ++i)
                nv[i] = *(const float4*)(mfb + (size_t)((kk + 1) * 32 + stg_k + i * 4) * NPX + px0 + stg_px4);
        }

        bf16x8 bf[4];
        #pragma unroll
        for (int ct = 0; ct < 4; ++ct)
            #pragma unroll
            for (int j = 0; j < 8; ++j)
                bf[ct][j] = (short)Bs[cur + (lg * 8 + j) * B_STRIDE + pxF + ct * 16];

        #pragma unroll
        for (int st = 0; st < 4; ++st) {
            if (st < st_max) {
                const bf16x8 af = *(const bf16x8*)&As[(st * 16 + ll) * A_STRIDE + kk * 32 + lg * 8];
                #pragma unroll
                for (int ct = 0; ct < 4; ++ct)
                    acc[st][ct] = __builtin_amdgcn_mfma_f32_16x16x32_bf16(af, bf[ct], acc[st][ct], 0, 0, 0);
            }
        }

        if (kk < 7) {
            const int nxt = ((kk + 1) & 1) * B_BUF;
            #pragma unroll
            for (int i = 0; i < 8; ++i) {
                bf16x4 pv;
                pv[0] = (short)f2bf(nv[i].x); pv[1] = (short)f2bf(nv[i].y);
                pv[2] = (short)f2bf(nv[i].z); pv[3] = (short)f2bf(nv[i].w);
                *(bf16x4*)&Bs[nxt + (stg_k + i * 4) * B_STRIDE + stg_px4] = pv;
            }
        }
        __syncthreads();
    }

    #pragma unroll
    for (int st = 0; st < 4; ++st) {
        if (st < st_max) {
            #pragma unroll
            for (int ct = 0; ct < 4; ++ct) {
                #pragma unroll
                for (int r = 0; r < 4; ++r) {
                    const int s = s_base + st * 16 + lg * 4 + r;
                    if (s < NS)
                        outm[((size_t)(b * NS + s)) * NPX + px0 + wv * 64 + ct * 16 + ll] = acc[st][ct][r];
                }
            }
        }
    }
}

extern "C" void kernel_launch(void* const* d_in, const int* in_sizes, int n_in,
                              void* d_out, int out_size, void* d_ws, size_t ws_size,
                              hipStream_t stream) {
    const float* qcls = (const float*)d_in[0];
    const float* qemb = (const float*)d_in[1];
    const float* qsig = (const float*)d_in[2];
    const float* seed = (const float*)d_in[3];
    const float* mf   = (const float*)d_in[4];
    const int*   mask = (const int*)d_in[5];

    float* out       = (float*)d_out;
    float* out_cls   = out;
    float* out_masks = out + MASKS_BASE;
    float* out_emb   = out + EMB_BASE;

    float* w    = (float*)d_ws;                    // [4][100][2700]
    float* dsum = w + (size_t)NB * NS * LQ;        // [400]

    hipMemsetAsync(out_cls, 0, (size_t)NB * NS * NCLS * sizeof(float), stream);
    hipMemsetAsync(out_emb, 0, (size_t)NB * NS * NC * sizeof(float), stream);
    hipMemsetAsync(dsum,    0, (size_t)NB * NS * sizeof(float), stream);

    k_sim_mfma<<<dim3(22, NB, 2), 256, 0, stream>>>(qsig, seed, mask, w, dsum);
    k_embcls  <<<dim3(6, NB, 22), 256, 0, stream>>>(w, qemb, qcls, out_emb, out_cls);
    k_fin     <<<527,             256, 0, stream>>>(out, dsum);
    k_masks_mfma<<<800, 256, 0, stream>>>(out_emb, mf, out_masks);
}

// Round 17
// 103.391 us; speedup vs baseline: 1.3963x; 1.2170x over previous
//
#include <hip/hip_runtime.h>
#include <hip/hip_bf16.h>

#define NB   4
#define NL   9
#define NQ   300
#define LQ   2700
#define NS   100
#define NC   256
#define NCLS 81
#define NPX  25600
#define EPSV 1e-6f

#define MASKS_BASE 32400
#define EMB_BASE   10272400   // 32400 + 4*100*160*160

#define A_STRIDE 264          // bf16 elems; 528B rows: 16B-aligned, 4-bank rotation
#define B_STRIDE 260          // bf16 elems per k-row of B_lds (256 px + 4 pad)
#define B_BUF    (32 * B_STRIDE)
#define NPART    88           // dsum partials per (b,s): 22 qc x 4 waves

typedef short bf16x8 __attribute__((ext_vector_type(8)));
typedef short bf16x4 __attribute__((ext_vector_type(4)));
typedef float f32x4  __attribute__((ext_vector_type(4)));

__device__ inline unsigned short f2bf(float f) {
    __hip_bfloat16 h = __float2bfloat16(f);
    return *reinterpret_cast<unsigned short*>(&h);
}

// K1 (MFMA): sim = seed x qsig^T per b.  Round-14 body + fused output
// zeroing (prologue) + race-free dsum partials (epilogue, no atomics).
__global__ __launch_bounds__(256) void k_sim_mfma(const float* __restrict__ qsig,
                                                  const float* __restrict__ seed,
                                                  const int* __restrict__ mask,
                                                  float* __restrict__ w,
                                                  float* __restrict__ dsumP,
                                                  float* __restrict__ out_cls,
                                                  float* __restrict__ out_emb) {
    __shared__ unsigned short As[64 * A_STRIDE];   // 33792 B

    const int b      = blockIdx.y;
    const int qc     = blockIdx.x;
    const int q0     = qc * 128;
    const int zhalf  = blockIdx.z;          // 0: s 0..63, 1: s 64..99
    const int s_base = zhalf * 64;
    const int st_max = 4 - zhalf;
    const int tid    = threadIdx.x;
    const float* seedb = seed + (size_t)b * NS * NC;

    // ---- fused zeroing of accumulation outputs (stream-ordered before
    //      k_embcls; 176 blocks x 256 threads >= 33700 float4s) ----
    {
        const int bid  = (blockIdx.z * 4 + blockIdx.y) * 22 + blockIdx.x;
        const int gid  = bid * 256 + tid;
        const float4 z4 = make_float4(0.f, 0.f, 0.f, 0.f);
        if (gid < 8100)  ((float4*)out_cls)[gid] = z4;   // 32400 f32
        if (gid < 25600) ((float4*)out_emb)[gid] = z4;   // 102400 f32
    }

    const int lane = tid & 63;
    const int wv   = tid >> 6;
    const int lg   = lane >> 4;
    const int ll   = lane & 15;

    const int qA = q0 + wv * 32 + ll;
    const int qB = qA + 16;
    const bool okA = (qA < LQ);
    const bool okB = (qB < LQ);
    const int qAc = okA ? qA : LQ - 1;
    const int qBc = okB ? qB : LQ - 1;
    const int lA = qAc / NQ, rA = qAc - lA * NQ;
    const int lB = qBc / NQ, rB = qBc - lB * NQ;
    const float* rowA = qsig + ((size_t)((lA * NB + b) * NQ + rA)) * NC;
    const float* rowB = qsig + ((size_t)((lB * NB + b) * NQ + rB)) * NC;

    float4 pA0 = *(const float4*)(rowA + lg * 8);
    float4 pA1 = *(const float4*)(rowA + lg * 8 + 4);
    float4 pB0 = *(const float4*)(rowB + lg * 8);
    float4 pB1 = *(const float4*)(rowB + lg * 8 + 4);

    const int rows_data = zhalf ? 36 : 64;
    for (int u = tid; u < rows_data * 64; u += 256) {
        const int s  = u >> 6;
        const int k4 = (u & 63) << 2;
        const float4 v = *(const float4*)(seedb + (size_t)(s_base + s) * NC + k4);
        bf16x4 pv;
        pv[0] = (short)f2bf(v.x); pv[1] = (short)f2bf(v.y);
        pv[2] = (short)f2bf(v.z); pv[3] = (short)f2bf(v.w);
        *(bf16x4*)&As[s * A_STRIDE + k4] = pv;
    }
    if (zhalf) {
        bf16x4 z; z[0] = 0; z[1] = 0; z[2] = 0; z[3] = 0;
        for (int u = tid; u < (12 * A_STRIDE) / 4; u += 256)
            *(bf16x4*)&As[36 * A_STRIDE + u * 4] = z;
    }
    __syncthreads();

    f32x4 acc[4][2];
    #pragma unroll
    for (int st = 0; st < 4; ++st) {
        acc[st][0] = (f32x4)(0.f);
        acc[st][1] = (f32x4)(0.f);
    }

    #pragma unroll
    for (int kk = 0; kk < 8; ++kk) {
        float4 nA0, nA1, nB0, nB1;
        if (kk < 7) {
            nA0 = *(const float4*)(rowA + (kk + 1) * 32 + lg * 8);
            nA1 = *(const float4*)(rowA + (kk + 1) * 32 + lg * 8 + 4);
            nB0 = *(const float4*)(rowB + (kk + 1) * 32 + lg * 8);
            nB1 = *(const float4*)(rowB + (kk + 1) * 32 + lg * 8 + 4);
        }

        bf16x8 bf0, bf1;
        bf0[0] = (short)f2bf(pA0.x); bf0[1] = (short)f2bf(pA0.y);
        bf0[2] = (short)f2bf(pA0.z); bf0[3] = (short)f2bf(pA0.w);
        bf0[4] = (short)f2bf(pA1.x); bf0[5] = (short)f2bf(pA1.y);
        bf0[6] = (short)f2bf(pA1.z); bf0[7] = (short)f2bf(pA1.w);
        bf1[0] = (short)f2bf(pB0.x); bf1[1] = (short)f2bf(pB0.y);
        bf1[2] = (short)f2bf(pB0.z); bf1[3] = (short)f2bf(pB0.w);
        bf1[4] = (short)f2bf(pB1.x); bf1[5] = (short)f2bf(pB1.y);
        bf1[6] = (short)f2bf(pB1.z); bf1[7] = (short)f2bf(pB1.w);
        if (!okA) {
            #pragma unroll
            for (int j = 0; j < 8; ++j) bf0[j] = 0;
        }
        if (!okB) {
            #pragma unroll
            for (int j = 0; j < 8; ++j) bf1[j] = 0;
        }

        #pragma unroll
        for (int st = 0; st < 4; ++st) {
            if (st < st_max) {
                const bf16x8 af = *(const bf16x8*)&As[(st * 16 + ll) * A_STRIDE + kk * 32 + lg * 8];
                acc[st][0] = __builtin_amdgcn_mfma_f32_16x16x32_bf16(af, bf0, acc[st][0], 0, 0, 0);
                acc[st][1] = __builtin_amdgcn_mfma_f32_16x16x32_bf16(af, bf1, acc[st][1], 0, 0, 0);
            }
        }

        pA0 = nA0; pA1 = nA1; pB0 = nB0; pB1 = nB1;
    }

    #pragma unroll
    for (int st = 0; st < 4; ++st) {
        if (st < st_max) {
            #pragma unroll
            for (int r = 0; r < 4; ++r) {
                const int s = s_base + st * 16 + lg * 4 + r;
                if (s < NS) {
                    const float vm = (mask[b * NS + s] != 0) ? 1.0f : 0.0f;
                    float v0 = acc[st][0][r]; v0 = (v0 > 0.f ? v0 : 0.f) * vm;
                    float v1 = acc[st][1][r]; v1 = (v1 > 0.f ? v1 : 0.f) * vm;
                    float* wrow = w + ((size_t)(b * NS + s)) * LQ;
                    if (okA) wrow[qA] = v0;
                    if (okB) wrow[qB] = v1;
                    float t = v0 + v1;
                    t += __shfl_xor(t, 1);
                    t += __shfl_xor(t, 2);
                    t += __shfl_xor(t, 4);
                    t += __shfl_xor(t, 8);
                    // race-free partial: slot written exactly once
                    if (ll == 0)
                        dsumP[((b * NS + s) * 22 + qc) * 4 + wv] = t;
                }
            }
        }
    }
}

// K3: fused emb+cls reduction over q, split-K atomics
__global__ __launch_bounds__(256) void k_embcls(const float* __restrict__ w,
                                                const float* __restrict__ qemb,
                                                const float* __restrict__ qcls,
                                                float* __restrict__ out_emb,
                                                float* __restrict__ out_cls) {
    __shared__ float W[NS * 128];
    const int t  = blockIdx.x;
    const int b  = blockIdx.y;
    const int qc = blockIdx.z;
    const int q0 = qc * 128;
    const int q1 = min(128, LQ - q0);

    for (int i = threadIdx.x; i < NS * 32; i += 256) {
        const int s  = i >> 5;
        const int q4 = (i & 31) << 2;
        if (q4 < q1)
            *(float4*)&W[s * 128 + q4] =
                *(const float4*)(w + ((size_t)(b * NS + s)) * LQ + q0 + q4);
    }
    __syncthreads();

    const int cl = threadIdx.x & 63;
    const int y  = threadIdx.x >> 6;
    const float* src; int ncols, c0; float* dst;
    if (t < 4) { src = qemb; ncols = NC;   c0 = t * 64;       dst = out_emb; }
    else       { src = qcls; ncols = NCLS; c0 = (t - 4) * 64; dst = out_cls; }
    const int  c   = c0 + cl;
    const bool act = (c < ncols);

    float acc[25];
    #pragma unroll
    for (int j = 0; j < 25; ++j) acc[j] = 0.f;

    for (int qq = 0; qq < q1; qq += 4) {
        float bv[4];
        #pragma unroll
        for (int k = 0; k < 4; ++k) {
            const int q = q0 + qq + k;
            const int l = q / NQ;
            const int r = q - l * NQ;
            bv[k] = act ? src[((size_t)((l * NB + b) * NQ + r)) * ncols + c] : 0.f;
        }
        const float* wp = &W[(y * 25) * 128 + qq];
        #pragma unroll
        for (int j = 0; j < 25; ++j) {
            const float4 wv = *(const float4*)(wp + j * 128);
            acc[j] = fmaf(wv.x, bv[0], fmaf(wv.y, bv[1],
                     fmaf(wv.z, bv[2], fmaf(wv.w, bv[3], acc[j]))));
        }
    }
    if (act) {
        #pragma unroll
        for (int j = 0; j < 25; ++j) {
            const int s = y * 25 + j;
            atomicAdd(dst + ((size_t)(b * NS + s)) * ncols + c, acc[j]);
        }
    }
}

// K4: scale accumulated sums by 1/max(sum(dsumP),eps) (deterministic sum)
__global__ __launch_bounds__(256) void k_fin(float* __restrict__ out,
                                             const float* __restrict__ dsumP) {
    const int i = blockIdx.x * 256 + threadIdx.x;
    int b, s; size_t idx;
    if (i < NB * NS * NCLS) {
        b = i / (NS * NCLS); s = (i / NCLS) % NS; idx = i;
    } else if (i < NB * NS * NCLS + NB * NS * NC) {
        const int j = i - NB * NS * NCLS;
        b = j / (NS * NC); s = (j >> 8) % NS; idx = (size_t)EMB_BASE + j;
    } else {
        return;
    }
    const float* p = dsumP + (size_t)(b * NS + s) * NPART;
    float d = 0.f;
    #pragma unroll 8
    for (int j = 0; j < NPART; ++j) d += p[j];
    out[idx] *= 1.0f / (d > EPSV ? d : EPSV);
}

// K5 (MFMA): proto_masks[b][s][px] = sum_c emb[b][s][c] * mf[b][c][px]
// Round-16 version (best measured): px-tile 256, B dbuf LDS, XCD swizzle
// with zhalf twins L2-adjacent.
__global__ __launch_bounds__(256, 2) void k_masks_mfma(const float* __restrict__ emb,
                                                       const float* __restrict__ mf,
                                                       float* __restrict__ outm) {
    __shared__ unsigned short As[64 * A_STRIDE];   // 33792 B
    __shared__ unsigned short Bs[2 * B_BUF];       // 33280 B  (total 67072)

    const int orig  = blockIdx.x;
    const int wgid  = (orig & 7) * 100 + (orig >> 3);
    const int zhalf = wgid & 1;
    const int rest  = wgid >> 1;
    const int pxt   = rest % 100;
    const int b     = rest / 100;

    const int px0    = pxt * 256;
    const int s_base = zhalf * 64;
    const int st_max = 4 - zhalf;
    const int tid    = threadIdx.x;
    const float* mfb  = mf  + (size_t)b * NC * NPX;
    const float* embb = emb + (size_t)b * NS * NC;

    const int lane = tid & 63;
    const int wv   = tid >> 6;
    const int lg   = lane >> 4;
    const int ll   = lane & 15;

    const int stg_k   = tid >> 6;
    const int stg_px4 = (tid & 63) << 2;

    float4 bv[8];
    #pragma unroll
    for (int i = 0; i < 8; ++i)
        bv[i] = *(const float4*)(mfb + (size_t)(stg_k + i * 4) * NPX + px0 + stg_px4);

    const int rows_data = zhalf ? 36 : 64;
    for (int u = tid; u < rows_data * 64; u += 256) {
        const int r  = u >> 6;
        const int k4 = (u & 63) << 2;
        const float4 v = *(const float4*)(embb + (size_t)(s_base + r) * NC + k4);
        bf16x4 pv;
        pv[0] = (short)f2bf(v.x); pv[1] = (short)f2bf(v.y);
        pv[2] = (short)f2bf(v.z); pv[3] = (short)f2bf(v.w);
        *(bf16x4*)&As[r * A_STRIDE + k4] = pv;
    }
    if (zhalf) {
        bf16x4 z; z[0] = 0; z[1] = 0; z[2] = 0; z[3] = 0;
        for (int u = tid; u < (12 * A_STRIDE) / 4; u += 256)
            *(bf16x4*)&As[36 * A_STRIDE + u * 4] = z;
    }

    #pragma unroll
    for (int i = 0; i < 8; ++i) {
        bf16x4 pv;
        pv[0] = (short)f2bf(bv[i].x); pv[1] = (short)f2bf(bv[i].y);
        pv[2] = (short)f2bf(bv[i].z); pv[3] = (short)f2bf(bv[i].w);
        *(bf16x4*)&Bs[(stg_k + i * 4) * B_STRIDE + stg_px4] = pv;
    }
    __syncthreads();

    f32x4 acc[4][4];
    #pragma unroll
    for (int st = 0; st < 4; ++st)
        #pragma unroll
        for (int ct = 0; ct < 4; ++ct) acc[st][ct] = (f32x4)(0.f);

    const int pxF = wv * 64 + ll;

    #pragma unroll
    for (int kk = 0; kk < 8; ++kk) {
        const int cur = (kk & 1) * B_BUF;

        float4 nv[8];
        if (kk < 7) {
            #pragma unroll
            for (int i = 0; i < 8; ++i)
                nv[i] = *(const float4*)(mfb + (size_t)((kk + 1) * 32 + stg_k + i * 4) * NPX + px0 + stg_px4);
        }

        bf16x8 bf[4];
        #pragma unroll
        for (int ct = 0; ct < 4; ++ct)
            #pragma unroll
            for (int j = 0; j < 8; ++j)
                bf[ct][j] = (short)Bs[cur + (lg * 8 + j) * B_STRIDE + pxF + ct * 16];

        #pragma unroll
        for (int st = 0; st < 4; ++st) {
            if (st < st_max) {
                const bf16x8 af = *(const bf16x8*)&As[(st * 16 + ll) * A_STRIDE + kk * 32 + lg * 8];
                #pragma unroll
                for (int ct = 0; ct < 4; ++ct)
                    acc[st][ct] = __builtin_amdgcn_mfma_f32_16x16x32_bf16(af, bf[ct], acc[st][ct], 0, 0, 0);
            }
        }

        if (kk < 7) {
            const int nxt = ((kk + 1) & 1) * B_BUF;
            #pragma unroll
            for (int i = 0; i < 8; ++i) {
                bf16x4 pv;
                pv[0] = (short)f2bf(nv[i].x); pv[1] = (short)f2bf(nv[i].y);
                pv[2] = (short)f2bf(nv[i].z); pv[3] = (short)f2bf(nv[i].w);
                *(bf16x4*)&Bs[nxt + (stg_k + i * 4) * B_STRIDE + stg_px4] = pv;
            }
        }
        __syncthreads();
    }

    #pragma unroll
    for (int st = 0; st < 4; ++st) {
        if (st < st_max) {
            #pragma unroll
            for (int ct = 0; ct < 4; ++ct) {
                #pragma unroll
                for (int r = 0; r < 4; ++r) {
                    const int s = s_base + st * 16 + lg * 4 + r;
                    if (s < NS)
                        outm[((size_t)(b * NS + s)) * NPX + px0 + wv * 64 + ct * 16 + ll] = acc[st][ct][r];
                }
            }
        }
    }
}

extern "C" void kernel_launch(void* const* d_in, const int* in_sizes, int n_in,
                              void* d_out, int out_size, void* d_ws, size_t ws_size,
                              hipStream_t stream) {
    const float* qcls = (const float*)d_in[0];
    const float* qemb = (const float*)d_in[1];
    const float* qsig = (const float*)d_in[2];
    const float* seed = (const float*)d_in[3];
    const float* mf   = (const float*)d_in[4];
    const int*   mask = (const int*)d_in[5];

    float* out       = (float*)d_out;
    float* out_cls   = out;
    float* out_masks = out + MASKS_BASE;
    float* out_emb   = out + EMB_BASE;

    float* w     = (float*)d_ws;                   // [4][100][2700]
    float* dsumP = w + (size_t)NB * NS * LQ;       // [400][88]

    k_sim_mfma<<<dim3(22, NB, 2), 256, 0, stream>>>(qsig, seed, mask, w, dsumP,
                                                    out_cls, out_emb);
    k_embcls  <<<dim3(6, NB, 22), 256, 0, stream>>>(w, qemb, qcls, out_emb, out_cls);
    k_fin     <<<527,             256, 0, stream>>>(out, dsumP);
    k_masks_mfma<<<800, 256, 0, stream>>>(out_emb, mf, out_masks);
}

// Round 18
// 101.092 us; speedup vs baseline: 1.4280x; 1.0227x over previous
//
#include <hip/hip_runtime.h>
#include <hip/hip_bf16.h>

#define NB   4
#define NL   9
#define NQ   300
#define LQ   2700
#define NS   100
#define NC   256
#define NCLS 81
#define NPX  25600
#define EPSV 1e-6f

#define MASKS_BASE 32400
#define EMB_BASE   10272400   // 32400 + 4*100*160*160

#define A_STRIDE 264          // bf16 elems; 528B rows: 16B-aligned, 4-bank rotation
#define B_STRIDE 260          // bf16 elems per k-row of B_lds (256 px + 4 pad)
#define B_BUF    (32 * B_STRIDE)
#define NPART    88           // dsum partials per (b,s): 22 qc x 4 waves

typedef short bf16x8 __attribute__((ext_vector_type(8)));
typedef short bf16x4 __attribute__((ext_vector_type(4)));
typedef float f32x4  __attribute__((ext_vector_type(4)));

__device__ inline unsigned short f2bf(float f) {
    __hip_bfloat16 h = __float2bfloat16(f);
    return *reinterpret_cast<unsigned short*>(&h);
}

// K1 (MFMA): sim = seed x qsig^T per b.  Round-17 version (passed, best).
// Fused output zeroing (prologue) + race-free dsum partials (no atomics).
__global__ __launch_bounds__(256) void k_sim_mfma(const float* __restrict__ qsig,
                                                  const float* __restrict__ seed,
                                                  const int* __restrict__ mask,
                                                  float* __restrict__ w,
                                                  float* __restrict__ dsumP,
                                                  float* __restrict__ out_cls,
                                                  float* __restrict__ out_emb) {
    __shared__ unsigned short As[64 * A_STRIDE];   // 33792 B

    const int b      = blockIdx.y;
    const int qc     = blockIdx.x;
    const int q0     = qc * 128;
    const int zhalf  = blockIdx.z;          // 0: s 0..63, 1: s 64..99
    const int s_base = zhalf * 64;
    const int st_max = 4 - zhalf;
    const int tid    = threadIdx.x;
    const float* seedb = seed + (size_t)b * NS * NC;

    // ---- fused zeroing of accumulation outputs ----
    {
        const int bid  = (blockIdx.z * 4 + blockIdx.y) * 22 + blockIdx.x;
        const int gid  = bid * 256 + tid;
        const float4 z4 = make_float4(0.f, 0.f, 0.f, 0.f);
        if (gid < 8100)  ((float4*)out_cls)[gid] = z4;   // 32400 f32
        if (gid < 25600) ((float4*)out_emb)[gid] = z4;   // 102400 f32
    }

    const int lane = tid & 63;
    const int wv   = tid >> 6;
    const int lg   = lane >> 4;
    const int ll   = lane & 15;

    const int qA = q0 + wv * 32 + ll;
    const int qB = qA + 16;
    const bool okA = (qA < LQ);
    const bool okB = (qB < LQ);
    const int qAc = okA ? qA : LQ - 1;
    const int qBc = okB ? qB : LQ - 1;
    const int lA = qAc / NQ, rA = qAc - lA * NQ;
    const int lB = qBc / NQ, rB = qBc - lB * NQ;
    const float* rowA = qsig + ((size_t)((lA * NB + b) * NQ + rA)) * NC;
    const float* rowB = qsig + ((size_t)((lB * NB + b) * NQ + rB)) * NC;

    float4 pA0 = *(const float4*)(rowA + lg * 8);
    float4 pA1 = *(const float4*)(rowA + lg * 8 + 4);
    float4 pB0 = *(const float4*)(rowB + lg * 8);
    float4 pB1 = *(const float4*)(rowB + lg * 8 + 4);

    const int rows_data = zhalf ? 36 : 64;
    for (int u = tid; u < rows_data * 64; u += 256) {
        const int s  = u >> 6;
        const int k4 = (u & 63) << 2;
        const float4 v = *(const float4*)(seedb + (size_t)(s_base + s) * NC + k4);
        bf16x4 pv;
        pv[0] = (short)f2bf(v.x); pv[1] = (short)f2bf(v.y);
        pv[2] = (short)f2bf(v.z); pv[3] = (short)f2bf(v.w);
        *(bf16x4*)&As[s * A_STRIDE + k4] = pv;
    }
    if (zhalf) {
        bf16x4 z; z[0] = 0; z[1] = 0; z[2] = 0; z[3] = 0;
        for (int u = tid; u < (12 * A_STRIDE) / 4; u += 256)
            *(bf16x4*)&As[36 * A_STRIDE + u * 4] = z;
    }
    __syncthreads();

    f32x4 acc[4][2];
    #pragma unroll
    for (int st = 0; st < 4; ++st) {
        acc[st][0] = (f32x4)(0.f);
        acc[st][1] = (f32x4)(0.f);
    }

    #pragma unroll
    for (int kk = 0; kk < 8; ++kk) {
        float4 nA0, nA1, nB0, nB1;
        if (kk < 7) {
            nA0 = *(const float4*)(rowA + (kk + 1) * 32 + lg * 8);
            nA1 = *(const float4*)(rowA + (kk + 1) * 32 + lg * 8 + 4);
            nB0 = *(const float4*)(rowB + (kk + 1) * 32 + lg * 8);
            nB1 = *(const float4*)(rowB + (kk + 1) * 32 + lg * 8 + 4);
        }

        bf16x8 bf0, bf1;
        bf0[0] = (short)f2bf(pA0.x); bf0[1] = (short)f2bf(pA0.y);
        bf0[2] = (short)f2bf(pA0.z); bf0[3] = (short)f2bf(pA0.w);
        bf0[4] = (short)f2bf(pA1.x); bf0[5] = (short)f2bf(pA1.y);
        bf0[6] = (short)f2bf(pA1.z); bf0[7] = (short)f2bf(pA1.w);
        bf1[0] = (short)f2bf(pB0.x); bf1[1] = (short)f2bf(pB0.y);
        bf1[2] = (short)f2bf(pB0.z); bf1[3] = (short)f2bf(pB0.w);
        bf1[4] = (short)f2bf(pB1.x); bf1[5] = (short)f2bf(pB1.y);
        bf1[6] = (short)f2bf(pB1.z); bf1[7] = (short)f2bf(pB1.w);
        if (!okA) {
            #pragma unroll
            for (int j = 0; j < 8; ++j) bf0[j] = 0;
        }
        if (!okB) {
            #pragma unroll
            for (int j = 0; j < 8; ++j) bf1[j] = 0;
        }

        #pragma unroll
        for (int st = 0; st < 4; ++st) {
            if (st < st_max) {
                const bf16x8 af = *(const bf16x8*)&As[(st * 16 + ll) * A_STRIDE + kk * 32 + lg * 8];
                acc[st][0] = __builtin_amdgcn_mfma_f32_16x16x32_bf16(af, bf0, acc[st][0], 0, 0, 0);
                acc[st][1] = __builtin_amdgcn_mfma_f32_16x16x32_bf16(af, bf1, acc[st][1], 0, 0, 0);
            }
        }

        pA0 = nA0; pA1 = nA1; pB0 = nB0; pB1 = nB1;
    }

    #pragma unroll
    for (int st = 0; st < 4; ++st) {
        if (st < st_max) {
            #pragma unroll
            for (int r = 0; r < 4; ++r) {
                const int s = s_base + st * 16 + lg * 4 + r;
                if (s < NS) {
                    const float vm = (mask[b * NS + s] != 0) ? 1.0f : 0.0f;
                    float v0 = acc[st][0][r]; v0 = (v0 > 0.f ? v0 : 0.f) * vm;
                    float v1 = acc[st][1][r]; v1 = (v1 > 0.f ? v1 : 0.f) * vm;
                    float* wrow = w + ((size_t)(b * NS + s)) * LQ;
                    if (okA) wrow[qA] = v0;
                    if (okB) wrow[qB] = v1;
                    float t = v0 + v1;
                    t += __shfl_xor(t, 1);
                    t += __shfl_xor(t, 2);
                    t += __shfl_xor(t, 4);
                    t += __shfl_xor(t, 8);
                    if (ll == 0)
                        dsumP[((b * NS + s) * 22 + qc) * 4 + wv] = t;
                }
            }
        }
    }
}

// K3: fused emb+cls reduction over q, split-K atomics.
// rcp FUSED: each block sums the 88 dsumP partials per s (deterministic,
// L2-hot) and scales its contributions -> outputs arrive finalized (k_fin
// eliminated; scaling commutes with the atomic sum).
__global__ __launch_bounds__(256) void k_embcls(const float* __restrict__ w,
                                                const float* __restrict__ qemb,
                                                const float* __restrict__ qcls,
                                                const float* __restrict__ dsumP,
                                                float* __restrict__ out_emb,
                                                float* __restrict__ out_cls) {
    __shared__ float W[NS * 128];
    __shared__ float R[NS];
    const int t  = blockIdx.x;
    const int b  = blockIdx.y;
    const int qc = blockIdx.z;
    const int q0 = qc * 128;
    const int q1 = min(128, LQ - q0);

    for (int i = threadIdx.x; i < NS * 32; i += 256) {
        const int s  = i >> 5;
        const int q4 = (i & 31) << 2;
        if (q4 < q1)
            *(float4*)&W[s * 128 + q4] =
                *(const float4*)(w + ((size_t)(b * NS + s)) * LQ + q0 + q4);
    }
    if (threadIdx.x < NS) {
        const float* p = dsumP + (size_t)(b * NS + threadIdx.x) * NPART;
        float d = 0.f;
        #pragma unroll 8
        for (int j = 0; j < NPART; ++j) d += p[j];
        R[threadIdx.x] = 1.0f / (d > EPSV ? d : EPSV);
    }
    __syncthreads();

    const int cl = threadIdx.x & 63;
    const int y  = threadIdx.x >> 6;
    const float* src; int ncols, c0; float* dst;
    if (t < 4) { src = qemb; ncols = NC;   c0 = t * 64;       dst = out_emb; }
    else       { src = qcls; ncols = NCLS; c0 = (t - 4) * 64; dst = out_cls; }
    const int  c   = c0 + cl;
    const bool act = (c < ncols);

    float acc[25];
    #pragma unroll
    for (int j = 0; j < 25; ++j) acc[j] = 0.f;

    for (int qq = 0; qq < q1; qq += 4) {
        float bv[4];
        #pragma unroll
        for (int k = 0; k < 4; ++k) {
            const int q = q0 + qq + k;
            const int l = q / NQ;
            const int r = q - l * NQ;
            bv[k] = act ? src[((size_t)((l * NB + b) * NQ + r)) * ncols + c] : 0.f;
        }
        const float* wp = &W[(y * 25) * 128 + qq];
        #pragma unroll
        for (int j = 0; j < 25; ++j) {
            const float4 wv = *(const float4*)(wp + j * 128);
            acc[j] = fmaf(wv.x, bv[0], fmaf(wv.y, bv[1],
                     fmaf(wv.z, bv[2], fmaf(wv.w, bv[3], acc[j]))));
        }
    }
    if (act) {
        #pragma unroll
        for (int j = 0; j < 25; ++j) {
            const int s = y * 25 + j;
            atomicAdd(dst + ((size_t)(b * NS + s)) * ncols + c, acc[j] * R[s]);
        }
    }
}

// K5 (MFMA): proto_masks[b][s][px] = sum_c emb[b][s][c] * mf[b][c][px]
// Round-16/17 version (best measured): px-tile 256, B dbuf LDS, XCD
// swizzle with zhalf twins L2-adjacent.
__global__ __launch_bounds__(256, 2) void k_masks_mfma(const float* __restrict__ emb,
                                                       const float* __restrict__ mf,
                                                       float* __restrict__ outm) {
    __shared__ unsigned short As[64 * A_STRIDE];   // 33792 B
    __shared__ unsigned short Bs[2 * B_BUF];       // 33280 B  (total 67072)

    const int orig  = blockIdx.x;
    const int wgid  = (orig & 7) * 100 + (orig >> 3);
    const int zhalf = wgid & 1;
    const int rest  = wgid >> 1;
    const int pxt   = rest % 100;
    const int b     = rest / 100;

    const int px0    = pxt * 256;
    const int s_base = zhalf * 64;
    const int st_max = 4 - zhalf;
    const int tid    = threadIdx.x;
    const float* mfb  = mf  + (size_t)b * NC * NPX;
    const float* embb = emb + (size_t)b * NS * NC;

    const int lane = tid & 63;
    const int wv   = tid >> 6;
    const int lg   = lane >> 4;
    const int ll   = lane & 15;

    const int stg_k   = tid >> 6;
    const int stg_px4 = (tid & 63) << 2;

    float4 bv[8];
    #pragma unroll
    for (int i = 0; i < 8; ++i)
        bv[i] = *(const float4*)(mfb + (size_t)(stg_k + i * 4) * NPX + px0 + stg_px4);

    const int rows_data = zhalf ? 36 : 64;
    for (int u = tid; u < rows_data * 64; u += 256) {
        const int r  = u >> 6;
        const int k4 = (u & 63) << 2;
        const float4 v = *(const float4*)(embb + (size_t)(s_base + r) * NC + k4);
        bf16x4 pv;
        pv[0] = (short)f2bf(v.x); pv[1] = (short)f2bf(v.y);
        pv[2] = (short)f2bf(v.z); pv[3] = (short)f2bf(v.w);
        *(bf16x4*)&As[r * A_STRIDE + k4] = pv;
    }
    if (zhalf) {
        bf16x4 z; z[0] = 0; z[1] = 0; z[2] = 0; z[3] = 0;
        for (int u = tid; u < (12 * A_STRIDE) / 4; u += 256)
            *(bf16x4*)&As[36 * A_STRIDE + u * 4] = z;
    }

    #pragma unroll
    for (int i = 0; i < 8; ++i) {
        bf16x4 pv;
        pv[0] = (short)f2bf(bv[i].x); pv[1] = (short)f2bf(bv[i].y);
        pv[2] = (short)f2bf(bv[i].z); pv[3] = (short)f2bf(bv[i].w);
        *(bf16x4*)&Bs[(stg_k + i * 4) * B_STRIDE + stg_px4] = pv;
    }
    __syncthreads();

    f32x4 acc[4][4];
    #pragma unroll
    for (int st = 0; st < 4; ++st)
        #pragma unroll
        for (int ct = 0; ct < 4; ++ct) acc[st][ct] = (f32x4)(0.f);

    const int pxF = wv * 64 + ll;

    #pragma unroll
    for (int kk = 0; kk < 8; ++kk) {
        const int cur = (kk & 1) * B_BUF;

        float4 nv[8];
        if (kk < 7) {
            #pragma unroll
            for (int i = 0; i < 8; ++i)
                nv[i] = *(const float4*)(mfb + (size_t)((kk + 1) * 32 + stg_k + i * 4) * NPX + px0 + stg_px4);
        }

        bf16x8 bf[4];
        #pragma unroll
        for (int ct = 0; ct < 4; ++ct)
            #pragma unroll
            for (int j = 0; j < 8; ++j)
                bf[ct][j] = (short)Bs[cur + (lg * 8 + j) * B_STRIDE + pxF + ct * 16];

        #pragma unroll
        for (int st = 0; st < 4; ++st) {
            if (st < st_max) {
                const bf16x8 af = *(const bf16x8*)&As[(st * 16 + ll) * A_STRIDE + kk * 32 + lg * 8];
                #pragma unroll
                for (int ct = 0; ct < 4; ++ct)
                    acc[st][ct] = __builtin_amdgcn_mfma_f32_16x16x32_bf16(af, bf[ct], acc[st][ct], 0, 0, 0);
            }
        }

        if (kk < 7) {
            const int nxt = ((kk + 1) & 1) * B_BUF;
            #pragma unroll
            for (int i = 0; i < 8; ++i) {
                bf16x4 pv;
                pv[0] = (short)f2bf(nv[i].x); pv[1] = (short)f2bf(nv[i].y);
                pv[2] = (short)f2bf(nv[i].z); pv[3] = (short)f2bf(nv[i].w);
                *(bf16x4*)&Bs[nxt + (stg_k + i * 4) * B_STRIDE + stg_px4] = pv;
            }
        }
        __syncthreads();
    }

    #pragma unroll
    for (int st = 0; st < 4; ++st) {
        if (st < st_max) {
            #pragma unroll
            for (int ct = 0; ct < 4; ++ct) {
                #pragma unroll
                for (int r = 0; r < 4; ++r) {
                    const int s = s_base + st * 16 + lg * 4 + r;
                    if (s < NS)
                        outm[((size_t)(b * NS + s)) * NPX + px0 + wv * 64 + ct * 16 + ll] = acc[st][ct][r];
                }
            }
        }
    }
}

extern "C" void kernel_launch(void* const* d_in, const int* in_sizes, int n_in,
                              void* d_out, int out_size, void* d_ws, size_t ws_size,
                              hipStream_t stream) {
    const float* qcls = (const float*)d_in[0];
    const float* qemb = (const float*)d_in[1];
    const float* qsig = (const float*)d_in[2];
    const float* seed = (const float*)d_in[3];
    const float* mf   = (const float*)d_in[4];
    const int*   mask = (const int*)d_in[5];

    float* out       = (float*)d_out;
    float* out_cls   = out;
    float* out_masks = out + MASKS_BASE;
    float* out_emb   = out + EMB_BASE;

    float* w     = (float*)d_ws;                   // [4][100][2700]
    float* dsumP = w + (size_t)NB * NS * LQ;       // [400][88]

    k_sim_mfma<<<dim3(22, NB, 2), 256, 0, stream>>>(qsig, seed, mask, w, dsumP,
                                                    out_cls, out_emb);
    k_embcls  <<<dim3(6, NB, 22), 256, 0, stream>>>(w, qemb, qcls, dsumP,
                                                    out_emb, out_cls);
    k_masks_mfma<<<800, 256, 0, stream>>>(out_emb, mf, out_masks);
}